// Round 10
// baseline (212.970 us; speedup 1.0000x reference)
//
#include <hip/hip_runtime.h>
#include <math.h>

#define NN   4096
#define DD   512
#define TWON 8192
#define KSLICE 4

typedef _Float16 half_t;
using half8 = __attribute__((ext_vector_type(8))) half_t;
using f32x4 = __attribute__((ext_vector_type(4))) float;

__device__ __forceinline__ void gl16(const void* g, void* l) {
    __builtin_amdgcn_global_load_lds(
        (const __attribute__((address_space(1))) void*)g,
        (__attribute__((address_space(3))) void*)l, 16, 0, 0);
}
__device__ __forceinline__ f32x4 mfma16h(half8 a, half8 b, f32x4 c) {
    return __builtin_amdgcn_mfma_f32_16x16x32_f16(a, b, c, 0, 0, 0);
}

// ---------------- prep: b=[y;x] -> f16 + norms nb[8192]
__global__ __launch_bounds__(64)
void prep_k(const float* __restrict__ x, const float* __restrict__ y,
            half_t* __restrict__ bhi, float* __restrict__ nb) {
    int r = blockIdx.x;           // 0..8191
    int l = threadIdx.x;          // 64
    const float* src = (r < NN) ? (y + (size_t)r * DD) : (x + (size_t)(r - NN) * DD);
    float4 v0 = *reinterpret_cast<const float4*>(src + l * 8);
    float4 v1 = *reinterpret_cast<const float4*>(src + l * 8 + 4);
    float e[8] = {v0.x, v0.y, v0.z, v0.w, v1.x, v1.y, v1.z, v1.w};
    float s = 0.f;
    half8 h;
    #pragma unroll
    for (int q = 0; q < 8; ++q) {
        s += e[q] * e[q];
        h[q] = (half_t)e[q];
    }
    *reinterpret_cast<half8*>(bhi + (size_t)r * DD + l * 8) = h;
    #pragma unroll
    for (int off = 32; off; off >>= 1) s += __shfl_down(s, off);
    if (l == 0) nb[r] = s;
}

// ---------------- b2t: b2t[d][k] = k<N ? y[k][d] : -x[k-N][d]  (f16, 512x8192)
__global__ __launch_bounds__(256)
void b2t_k(const float* __restrict__ x, const float* __restrict__ y, half_t* __restrict__ b2t) {
    __shared__ float tl[32][33];
    int k0 = blockIdx.x * 32, d0 = blockIdx.y * 32;
    int tx = threadIdx.x, ty = threadIdx.y;   // (32,8)
    const float* src = (k0 < NN) ? y : x;
    int row0 = (k0 < NN) ? k0 : (k0 - NN);
    #pragma unroll
    for (int j = 0; j < 4; ++j)
        tl[ty + 8 * j][tx] = src[(size_t)(row0 + ty + 8 * j) * DD + d0 + tx];
    __syncthreads();
    float sgn = (k0 < NN) ? 1.f : -1.f;
    #pragma unroll
    for (int j = 0; j < 4; ++j) {
        float v = tl[tx][ty + 8 * j] * sgn;
        b2t[(size_t)(d0 + ty + 8 * j) * TWON + k0 + tx] = (half_t)v;
    }
}

// ---------------- GEMM1: f16 MFMA + logits; stores E=exp(l-rmt)*1024 (f16),
// rpm = per-(jtile,row) max rmt, rps = row sums rel. rmt,
// cpm = tile max C, cps = col sums rel. C.
__global__ __launch_bounds__(256)
void gemm1_k(const half_t* __restrict__ bhi,
             const float* __restrict__ nb, half_t* __restrict__ Ef,
             float* __restrict__ rpm, float* __restrict__ rps,
             float* __restrict__ cpm, float* __restrict__ cps) {
    __shared__ unsigned char lds[32768]; // Ahi@0 Bhi@16K, each 128x64 f16 swizzled
    const int t = threadIdx.x;
    const int wave = t >> 6, lane = t & 63;
    const int i0 = blockIdx.y * 128, j0 = blockIdx.x * 128;
    const int wm = (wave >> 1) * 64, wn = (wave & 1) * 64;
    const half_t* ahig = bhi + (size_t)NN * DD;  // x rows are b rows 4096..8191
    f32x4 acc[4][4] = {};
    for (int k0 = 0; k0 < DD; k0 += 64) {
        __syncthreads();
        #pragma unroll
        for (int q = 0; q < 4; ++q) {
            const int dbase = (wave * 4 + q) * 1024;
            const int p  = dbase + lane * 16;
            const int r  = p >> 7;
            const int cb = (p & 127) ^ ((r & 7) << 4);
            const size_t offA = (size_t)(i0 + r) * DD + k0 + (cb >> 1);
            const size_t offB = (size_t)(j0 + r) * DD + k0 + (cb >> 1);
            gl16(ahig + offA, lds + dbase);
            gl16(bhi  + offB, lds + 16384 + dbase);
        }
        asm volatile("s_waitcnt vmcnt(0)" ::: "memory");
        __builtin_amdgcn_sched_barrier(0);
        __syncthreads();
        #pragma unroll
        for (int kk = 0; kk < 2; ++kk) {
            half8 ah[4];
            #pragma unroll
            for (int m = 0; m < 4; ++m) {
                const int row = wm + m * 16 + (lane & 15);
                const int off = row * 128 + ((kk * 64 + (lane >> 4) * 16) ^ ((row & 7) << 4));
                ah[m] = *reinterpret_cast<const half8*>(lds + off);
            }
            #pragma unroll
            for (int n = 0; n < 4; ++n) {
                const int row = wn + n * 16 + (lane & 15);
                const int off = row * 128 + ((kk * 64 + (lane >> 4) * 16) ^ ((row & 7) << 4));
                half8 bh = *reinterpret_cast<const half8*>(lds + 16384 + off);
                #pragma unroll
                for (int m = 0; m < 4; ++m)
                    acc[m][n] = mfma16h(ah[m], bh, acc[m][n]);
            }
        }
    }
    // ---- pass 1: acc -> logits (in acc)
    float nbj[4];
    #pragma unroll
    for (int n = 0; n < 4; ++n) nbj[n] = nb[j0 + wn + n * 16 + (lane & 15)];
    #pragma unroll
    for (int m = 0; m < 4; ++m) {
        #pragma unroll
        for (int r4 = 0; r4 < 4; ++r4) {
            const int i = i0 + wm + m * 16 + (lane >> 4) * 4 + r4;
            const float nxi = nb[NN + i];
            #pragma unroll
            for (int n = 0; n < 4; ++n) {
                const int j = j0 + wn + n * 16 + (lane & 15);
                float sq = nxi + nbj[n] - 2.0f * acc[m][n][r4];
                float lg = -10.0f * sqrtf(fmaxf(sq, 1e-12f));
                if (j == i + NN) lg = -1e7f;
                acc[m][n][r4] = lg;
            }
        }
    }
    // ---- per-row max over this wave's 64 cols
    float rmx[16];
    #pragma unroll
    for (int m = 0; m < 4; ++m)
        #pragma unroll
        for (int r4 = 0; r4 < 4; ++r4)
            rmx[m * 4 + r4] = fmaxf(fmaxf(acc[m][0][r4], acc[m][1][r4]),
                                    fmaxf(acc[m][2][r4], acc[m][3][r4]));
    #pragma unroll
    for (int off = 1; off < 16; off <<= 1)
        #pragma unroll
        for (int idx = 0; idx < 16; ++idx)
            rmx[idx] = fmaxf(rmx[idx], __shfl_xor(rmx[idx], off));
    // ---- exchange halves -> full-tile row max rmt
    __syncthreads();
    float* red = reinterpret_cast<float*>(lds);
    if ((lane & 15) == 0) {
        #pragma unroll
        for (int m = 0; m < 4; ++m)
            #pragma unroll
            for (int r4 = 0; r4 < 4; ++r4) {
                const int r = wm + m * 16 + (lane >> 4) * 4 + r4;
                red[(wave & 1) * 128 + r] = rmx[m * 4 + r4];
            }
    }
    __syncthreads();
    float rmt[16];
    #pragma unroll
    for (int m = 0; m < 4; ++m)
        #pragma unroll
        for (int r4 = 0; r4 < 4; ++r4) {
            const int r = wm + m * 16 + (lane >> 4) * 4 + r4;
            rmt[m * 4 + r4] = fmaxf(rmx[m * 4 + r4], red[(((wave & 1) ^ 1)) * 128 + r]);
        }
    // ---- E = exp(l - rmt); store Ef*2^10; row sums (plain adds, shared ref)
    float rs[16] = {};
    #pragma unroll
    for (int m = 0; m < 4; ++m) {
        #pragma unroll
        for (int r4 = 0; r4 < 4; ++r4) {
            const int idx = m * 4 + r4;
            const int i = i0 + wm + m * 16 + (lane >> 4) * 4 + r4;
            #pragma unroll
            for (int n = 0; n < 4; ++n) {
                const int j = j0 + wn + n * 16 + (lane & 15);
                float e = __expf(acc[m][n][r4] - rmt[idx]);
                acc[m][n][r4] = e;
                Ef[(size_t)i * TWON + j] = (half_t)(e * 1024.0f);
                rs[idx] += e;
            }
        }
    }
    #pragma unroll
    for (int off = 1; off < 16; off <<= 1)
        #pragma unroll
        for (int idx = 0; idx < 16; ++idx) rs[idx] += __shfl_xor(rs[idx], off);
    // ---- tile max C
    float tmax = rmt[0];
    #pragma unroll
    for (int idx = 1; idx < 16; ++idx) tmax = fmaxf(tmax, rmt[idx]);
    tmax = fmaxf(tmax, __shfl_xor(tmax, 16));
    tmax = fmaxf(tmax, __shfl_xor(tmax, 32));
    __syncthreads();               // rmt reads done; red reusable
    if (((wave & 1) == 0) && (lane & 15) == 0) {
        #pragma unroll
        for (int m = 0; m < 4; ++m)
            #pragma unroll
            for (int r4 = 0; r4 < 4; ++r4) {
                const int r = wm + m * 16 + (lane >> 4) * 4 + r4;
                red[r] = rmt[m * 4 + r4];             // rmt per row
            }
    }
    if ((lane & 15) == 0) {
        #pragma unroll
        for (int m = 0; m < 4; ++m)
            #pragma unroll
            for (int r4 = 0; r4 < 4; ++r4) {
                const int r = wm + m * 16 + (lane >> 4) * 4 + r4;
                red[128 + (wave & 1) * 128 + r] = rs[m * 4 + r4];  // rs halves
            }
    }
    if (lane == 0) red[384 + wave] = tmax;
    __syncthreads();
    const float C = fmaxf(fmaxf(red[384], red[385]), fmaxf(red[386], red[387]));
    // ---- col partials relative to C: cs = sum_i E * exp(rmt_i - C)
    float w[16];
    #pragma unroll
    for (int idx = 0; idx < 16; ++idx) w[idx] = __expf(rmt[idx] - C);
    float cs[4] = {};
    #pragma unroll
    for (int m = 0; m < 4; ++m)
        #pragma unroll
        for (int r4 = 0; r4 < 4; ++r4)
            #pragma unroll
            for (int n = 0; n < 4; ++n)
                cs[n] = fmaf(acc[m][n][r4], w[m * 4 + r4], cs[n]);
    #pragma unroll
    for (int off = 16; off < 64; off <<= 1)
        #pragma unroll
        for (int n = 0; n < 4; ++n) cs[n] += __shfl_xor(cs[n], off);
    if (lane < 16) {
        #pragma unroll
        for (int n = 0; n < 4; ++n) {
            const int c = wn + n * 16 + lane;
            red[512 + (wave >> 1) * 128 + c] = cs[n];
        }
    }
    __syncthreads();
    if (t < 128) {
        rpm[(size_t)blockIdx.x * NN + i0 + t] = red[t];
        rps[(size_t)blockIdx.x * NN + i0 + t] = red[128 + t] + red[256 + t];
    } else {
        const int c = t - 128;
        cpm[(size_t)blockIdx.y * TWON + j0 + c] = C;
        cps[(size_t)blockIdx.y * TWON + j0 + c] = red[512 + c] + red[640 + c];
    }
}

// ---------------- combine row partials (64 j-tiles, online) -> rm, rrs
__global__ __launch_bounds__(256)
void row_comb_k(const float* __restrict__ rpm, const float* __restrict__ rps,
                float* __restrict__ rm, float* __restrict__ rrs) {
    int i = blockIdx.x * 256 + threadIdx.x;
    float M = -3.0e38f;
    for (int tt = 0; tt < TWON / 128; ++tt) M = fmaxf(M, rpm[(size_t)tt * NN + i]);
    float S = 0.f;
    for (int tt = 0; tt < TWON / 128; ++tt)
        S += rps[(size_t)tt * NN + i] * __expf(rpm[(size_t)tt * NN + i] - M);
    rm[i] = M; rrs[i] = rsqrtf(S);
}

// ---------------- combine col partials (32 i-tiles) -> cm, rcs
__global__ __launch_bounds__(256)
void col_comb_k(const float* __restrict__ cpm, const float* __restrict__ cps,
                float* __restrict__ cm, float* __restrict__ rcs) {
    int j = blockIdx.x * 256 + threadIdx.x;
    float M = -3.0e38f;
    for (int tt = 0; tt < NN / 128; ++tt) M = fmaxf(M, cpm[(size_t)tt * TWON + j]);
    float S = 0.f;
    for (int tt = 0; tt < NN / 128; ++tt)
        S += cps[(size_t)tt * TWON + j] * __expf(cpm[(size_t)tt * TWON + j] - M);
    cm[j] = M; rcs[j] = rsqrtf(S);
}

// ---------------- transform: Ef *= exp(rmt[i][jb] - rm_i/2 - cm_j/2)*rcs_j/1024
// -> stored value G = A / rrs_i  (rrs applied in gemm2 epilogue)
__global__ __launch_bounds__(256)
void transform_k(half_t* __restrict__ Ef, const float* __restrict__ rpm,
                 const float* __restrict__ rm,
                 const float* __restrict__ cm, const float* __restrict__ rcs) {
    const size_t nidx8 = (size_t)NN * TWON / 8;
    const size_t stride = (size_t)gridDim.x * 256;
    for (size_t idx = (size_t)blockIdx.x * 256 + threadIdx.x; idx < nidx8; idx += stride) {
        const size_t base = idx * 8;
        const int i = (int)(base >> 13);
        const int j = (int)(base & 8191);
        const int jb = j >> 7;
        const float arg0 = rpm[(size_t)jb * NN + i] - 0.5f * rm[i];
        half8 e = *reinterpret_cast<half8*>(Ef + base);
        float4 c0 = *reinterpret_cast<const float4*>(cm + j);
        float4 c1 = *reinterpret_cast<const float4*>(cm + j + 4);
        float4 r0 = *reinterpret_cast<const float4*>(rcs + j);
        float4 r1 = *reinterpret_cast<const float4*>(rcs + j + 4);
        half8 o;
        o[0] = (half_t)((float)e[0] * (__expf(arg0 - 0.5f * c0.x) * r0.x * 9.765625e-4f));
        o[1] = (half_t)((float)e[1] * (__expf(arg0 - 0.5f * c0.y) * r0.y * 9.765625e-4f));
        o[2] = (half_t)((float)e[2] * (__expf(arg0 - 0.5f * c0.z) * r0.z * 9.765625e-4f));
        o[3] = (half_t)((float)e[3] * (__expf(arg0 - 0.5f * c0.w) * r0.w * 9.765625e-4f));
        o[4] = (half_t)((float)e[4] * (__expf(arg0 - 0.5f * c1.x) * r1.x * 9.765625e-4f));
        o[5] = (half_t)((float)e[5] * (__expf(arg0 - 0.5f * c1.y) * r1.y * 9.765625e-4f));
        o[6] = (half_t)((float)e[6] * (__expf(arg0 - 0.5f * c1.z) * r1.z * 9.765625e-4f));
        o[7] = (half_t)((float)e[7] * (__expf(arg0 - 0.5f * c1.w) * r1.w * 9.765625e-4f));
        *reinterpret_cast<half8*>(Ef + base) = o;
    }
}

// ---------------- GEMM2: split-K. A = G (f16) via gl16 dbuf LDS; B frags direct
// from L2; per-row rrs applied at epilogue. B loads issued FIRST each phase.
__global__ __launch_bounds__(512)
void gemm2_k(const half_t* __restrict__ Ef, const half_t* __restrict__ b2t,
             const float* __restrict__ rrs, float* __restrict__ part) {
    __shared__ unsigned char lds[16384];   // 2 x (64x64 f16 A tile, swizzled)
    const int t = threadIdx.x;
    const int wave = t >> 6, lane = t & 63;
    const int sw = blockIdx.x;             // 0..255
    const int xcd = sw & 7;
    const int kslice = xcd >> 1;           // 2 XCDs per kslice
    const int iblk = (sw >> 3) + (xcd & 1) * 32;
    const int i0 = iblk * 64;
    const int kbase = kslice * (TWON / KSLICE);
    const int wn = wave * 64;
    const int sr = t >> 3;
    const int scb = ((t & 7) * 16) ^ ((sr & 7) << 4);
    const size_t sga = (size_t)(i0 + sr) * TWON + (scb >> 1);
    const int NT = (TWON / KSLICE) / 64;   // 32
    f32x4 acc[4][4] = {};
    int cur = 0;
    gl16(Ef + sga + kbase, lds + t * 16);
    __syncthreads();
    for (int it = 0; it < NT; ++it) {
        half8 bfr0[4], bfr1[4];
        #pragma unroll
        for (int n = 0; n < 4; ++n) {
            const int d = wn + n * 16 + (lane & 15);
            const half_t* bp = b2t + (size_t)d * TWON + kbase + it * 64 + (lane >> 4) * 8;
            bfr0[n] = *reinterpret_cast<const half8*>(bp);
            bfr1[n] = *reinterpret_cast<const half8*>(bp + 32);
        }
        if (it + 1 < NT)
            gl16(Ef + sga + kbase + (it + 1) * 64, lds + ((cur ^ 1) * 8192) + t * 16);
        #pragma unroll
        for (int kk = 0; kk < 2; ++kk) {
            half8 af[4];
            #pragma unroll
            for (int m = 0; m < 4; ++m) {
                const int row = m * 16 + (lane & 15);
                const int off = cur * 8192 + row * 128 +
                                ((kk * 64 + (lane >> 4) * 16) ^ ((row & 7) << 4));
                af[m] = *reinterpret_cast<const half8*>(lds + off);
            }
            #pragma unroll
            for (int m = 0; m < 4; ++m)
                #pragma unroll
                for (int n = 0; n < 4; ++n)
                    acc[m][n] = mfma16h(af[m], (kk == 0) ? bfr0[n] : bfr1[n], acc[m][n]);
        }
        __syncthreads();
        cur ^= 1;
    }
    float* pout = part + (size_t)kslice * NN * DD;
    #pragma unroll
    for (int m = 0; m < 4; ++m) {
        float rf[4];
        #pragma unroll
        for (int r4 = 0; r4 < 4; ++r4) rf[r4] = rrs[i0 + m * 16 + (lane >> 4) * 4 + r4];
        #pragma unroll
        for (int n = 0; n < 4; ++n) {
            const int d = wn + n * 16 + (lane & 15);
            #pragma unroll
            for (int r4 = 0; r4 < 4; ++r4) {
                const int i = i0 + m * 16 + (lane >> 4) * 4 + r4;
                pout[(size_t)i * DD + d] = acc[m][n][r4] * rf[r4];
            }
        }
    }
}

// ---------------- reduce partials
__global__ __launch_bounds__(256)
void reduce_k(const float* __restrict__ part, float* __restrict__ out) {
    const size_t e4 = ((size_t)blockIdx.x * 256 + threadIdx.x) * 4;
    float4 a = *reinterpret_cast<const float4*>(part + e4);
    #pragma unroll
    for (int s = 1; s < KSLICE; ++s) {
        float4 b = *reinterpret_cast<const float4*>(part + (size_t)s * NN * DD + e4);
        a.x += b.x; a.y += b.y; a.z += b.z; a.w += b.w;
    }
    *reinterpret_cast<float4*>(out + e4) = a;
}

extern "C" void kernel_launch(void* const* d_in, const int* in_sizes, int n_in,
                              void* d_out, int out_size, void* d_ws, size_t ws_size,
                              hipStream_t stream) {
    const float* x = (const float*)d_in[0];
    const float* y = (const float*)d_in[1];
    float* out = (float*)d_out;

    char* w = (char*)d_ws;
    const size_t OFF_EF   = 0;                          // Ef f16: 64 MiB
    const size_t OFF_BHI  = 67108864;                   // bhi f16: 8 MiB
    const size_t OFF_B2T  = OFF_BHI + 8388608;          // b2t f16: 8 MiB (separate)
    const size_t OFF_PART = OFF_B2T + 8388608;          // part: 32 MiB
    const size_t OFF_RPM  = OFF_PART + 33554432;        // 1 MiB each
    const size_t OFF_RPS  = OFF_RPM + 1048576;
    const size_t OFF_CPM  = OFF_RPS + 1048576;
    const size_t OFF_CPS  = OFF_CPM + 1048576;
    const size_t OFF_TAIL = OFF_CPS + 1048576;

    half_t* Ef   = (half_t*)(w + OFF_EF);
    half_t* bhi  = (half_t*)(w + OFF_BHI);
    half_t* b2t  = (half_t*)(w + OFF_B2T);
    float*  part = (float*)(w + OFF_PART);
    float*  rpm  = (float*)(w + OFF_RPM);
    float*  rps  = (float*)(w + OFF_RPS);
    float*  cpm  = (float*)(w + OFF_CPM);
    float*  cps  = (float*)(w + OFF_CPS);
    float*  nb   = (float*)(w + OFF_TAIL);              // 8192
    float*  rm   = nb  + TWON;                          // 4096
    float*  rrs  = rm  + NN;                            // 4096
    float*  cm   = rrs + NN;                            // 8192
    float*  rcs  = cm  + TWON;                          // 8192

    prep_k<<<TWON, 64, 0, stream>>>(x, y, bhi, nb);
    gemm1_k<<<dim3(TWON / 128, NN / 128), 256, 0, stream>>>(bhi, nb, Ef,
                                                            rpm, rps, cpm, cps);
    row_comb_k<<<NN / 256, 256, 0, stream>>>(rpm, rps, rm, rrs);
    col_comb_k<<<TWON / 256, 256, 0, stream>>>(cpm, cps, cm, rcs);
    transform_k<<<2048, 256, 0, stream>>>(Ef, rpm, rm, cm, rcs);
    b2t_k<<<dim3(TWON / 32, DD / 32), dim3(32, 8), 0, stream>>>(x, y, b2t);
    gemm2_k<<<256, 512, 0, stream>>>(Ef, b2t, rrs, part);
    reduce_k<<<(NN * DD / 4) / 256, 256, 0, stream>>>(part, out);
}

// Round 11
// 195.879 us; speedup vs baseline: 1.0873x; 1.0873x over previous
//
#include <hip/hip_runtime.h>
#include <math.h>

#define NN   4096
#define DD   512
#define TWON 8192
#define KSLICE 8

typedef _Float16 half_t;
using half8 = __attribute__((ext_vector_type(8))) half_t;
using f32x4 = __attribute__((ext_vector_type(4))) float;

__device__ __forceinline__ void gl16(const void* g, void* l) {
    __builtin_amdgcn_global_load_lds(
        (const __attribute__((address_space(1))) void*)g,
        (__attribute__((address_space(3))) void*)l, 16, 0, 0);
}
__device__ __forceinline__ f32x4 mfma16h(half8 a, half8 b, f32x4 c) {
    return __builtin_amdgcn_mfma_f32_16x16x32_f16(a, b, c, 0, 0, 0);
}

// ---------------- prep: b=[y;x] -> f16 + norms nb[8192]
__global__ __launch_bounds__(64)
void prep_k(const float* __restrict__ x, const float* __restrict__ y,
            half_t* __restrict__ bhi, float* __restrict__ nb) {
    int r = blockIdx.x;           // 0..8191
    int l = threadIdx.x;          // 64
    const float* src = (r < NN) ? (y + (size_t)r * DD) : (x + (size_t)(r - NN) * DD);
    float4 v0 = *reinterpret_cast<const float4*>(src + l * 8);
    float4 v1 = *reinterpret_cast<const float4*>(src + l * 8 + 4);
    float e[8] = {v0.x, v0.y, v0.z, v0.w, v1.x, v1.y, v1.z, v1.w};
    float s = 0.f;
    half8 h;
    #pragma unroll
    for (int q = 0; q < 8; ++q) {
        s += e[q] * e[q];
        h[q] = (half_t)e[q];
    }
    *reinterpret_cast<half8*>(bhi + (size_t)r * DD + l * 8) = h;
    #pragma unroll
    for (int off = 32; off; off >>= 1) s += __shfl_down(s, off);
    if (l == 0) nb[r] = s;
}

// ---------------- b2t: b2t[d][k] = k<N ? y[k][d] : -x[k-N][d]  (f16, 512x8192)
__global__ __launch_bounds__(256)
void b2t_k(const float* __restrict__ x, const float* __restrict__ y, half_t* __restrict__ b2t) {
    __shared__ float tl[32][33];
    int k0 = blockIdx.x * 32, d0 = blockIdx.y * 32;
    int tx = threadIdx.x, ty = threadIdx.y;   // (32,8)
    const float* src = (k0 < NN) ? y : x;
    int row0 = (k0 < NN) ? k0 : (k0 - NN);
    #pragma unroll
    for (int j = 0; j < 4; ++j)
        tl[ty + 8 * j][tx] = src[(size_t)(row0 + ty + 8 * j) * DD + d0 + tx];
    __syncthreads();
    float sgn = (k0 < NN) ? 1.f : -1.f;
    #pragma unroll
    for (int j = 0; j < 4; ++j) {
        float v = tl[tx][ty + 8 * j] * sgn;
        b2t[(size_t)(d0 + ty + 8 * j) * TWON + k0 + tx] = (half_t)v;
    }
}

// ---------------- GEMM1: f16 MFMA + logits; stores E=exp(l-rmt)*1024 (f16),
// rpm = per-(jtile,row) max rmt, rps = row sums rel. rmt,
// cpm = tile max C, cps = col sums rel. C.   (verbatim round-10, twice-proven)
__global__ __launch_bounds__(256)
void gemm1_k(const half_t* __restrict__ bhi,
             const float* __restrict__ nb, half_t* __restrict__ Ef,
             float* __restrict__ rpm, float* __restrict__ rps,
             float* __restrict__ cpm, float* __restrict__ cps) {
    __shared__ unsigned char lds[32768]; // Ahi@0 Bhi@16K, each 128x64 f16 swizzled
    const int t = threadIdx.x;
    const int wave = t >> 6, lane = t & 63;
    const int i0 = blockIdx.y * 128, j0 = blockIdx.x * 128;
    const int wm = (wave >> 1) * 64, wn = (wave & 1) * 64;
    const half_t* ahig = bhi + (size_t)NN * DD;  // x rows are b rows 4096..8191
    f32x4 acc[4][4] = {};
    for (int k0 = 0; k0 < DD; k0 += 64) {
        __syncthreads();
        #pragma unroll
        for (int q = 0; q < 4; ++q) {
            const int dbase = (wave * 4 + q) * 1024;
            const int p  = dbase + lane * 16;
            const int r  = p >> 7;
            const int cb = (p & 127) ^ ((r & 7) << 4);
            const size_t offA = (size_t)(i0 + r) * DD + k0 + (cb >> 1);
            const size_t offB = (size_t)(j0 + r) * DD + k0 + (cb >> 1);
            gl16(ahig + offA, lds + dbase);
            gl16(bhi  + offB, lds + 16384 + dbase);
        }
        asm volatile("s_waitcnt vmcnt(0)" ::: "memory");
        __builtin_amdgcn_sched_barrier(0);
        __syncthreads();
        #pragma unroll
        for (int kk = 0; kk < 2; ++kk) {
            half8 ah[4];
            #pragma unroll
            for (int m = 0; m < 4; ++m) {
                const int row = wm + m * 16 + (lane & 15);
                const int off = row * 128 + ((kk * 64 + (lane >> 4) * 16) ^ ((row & 7) << 4));
                ah[m] = *reinterpret_cast<const half8*>(lds + off);
            }
            #pragma unroll
            for (int n = 0; n < 4; ++n) {
                const int row = wn + n * 16 + (lane & 15);
                const int off = row * 128 + ((kk * 64 + (lane >> 4) * 16) ^ ((row & 7) << 4));
                half8 bh = *reinterpret_cast<const half8*>(lds + 16384 + off);
                #pragma unroll
                for (int m = 0; m < 4; ++m)
                    acc[m][n] = mfma16h(ah[m], bh, acc[m][n]);
            }
        }
    }
    // ---- pass 1: acc -> logits (in acc)
    float nbj[4];
    #pragma unroll
    for (int n = 0; n < 4; ++n) nbj[n] = nb[j0 + wn + n * 16 + (lane & 15)];
    #pragma unroll
    for (int m = 0; m < 4; ++m) {
        #pragma unroll
        for (int r4 = 0; r4 < 4; ++r4) {
            const int i = i0 + wm + m * 16 + (lane >> 4) * 4 + r4;
            const float nxi = nb[NN + i];
            #pragma unroll
            for (int n = 0; n < 4; ++n) {
                const int j = j0 + wn + n * 16 + (lane & 15);
                float sq = nxi + nbj[n] - 2.0f * acc[m][n][r4];
                float lg = -10.0f * sqrtf(fmaxf(sq, 1e-12f));
                if (j == i + NN) lg = -1e7f;
                acc[m][n][r4] = lg;
            }
        }
    }
    // ---- per-row max over this wave's 64 cols
    float rmx[16];
    #pragma unroll
    for (int m = 0; m < 4; ++m)
        #pragma unroll
        for (int r4 = 0; r4 < 4; ++r4)
            rmx[m * 4 + r4] = fmaxf(fmaxf(acc[m][0][r4], acc[m][1][r4]),
                                    fmaxf(acc[m][2][r4], acc[m][3][r4]));
    #pragma unroll
    for (int off = 1; off < 16; off <<= 1)
        #pragma unroll
        for (int idx = 0; idx < 16; ++idx)
            rmx[idx] = fmaxf(rmx[idx], __shfl_xor(rmx[idx], off));
    // ---- exchange halves -> full-tile row max rmt
    __syncthreads();
    float* red = reinterpret_cast<float*>(lds);
    if ((lane & 15) == 0) {
        #pragma unroll
        for (int m = 0; m < 4; ++m)
            #pragma unroll
            for (int r4 = 0; r4 < 4; ++r4) {
                const int r = wm + m * 16 + (lane >> 4) * 4 + r4;
                red[(wave & 1) * 128 + r] = rmx[m * 4 + r4];
            }
    }
    __syncthreads();
    float rmt[16];
    #pragma unroll
    for (int m = 0; m < 4; ++m)
        #pragma unroll
        for (int r4 = 0; r4 < 4; ++r4) {
            const int r = wm + m * 16 + (lane >> 4) * 4 + r4;
            rmt[m * 4 + r4] = fmaxf(rmx[m * 4 + r4], red[(((wave & 1) ^ 1)) * 128 + r]);
        }
    // ---- E = exp(l - rmt); store Ef*2^10; row sums (plain adds, shared ref)
    float rs[16] = {};
    #pragma unroll
    for (int m = 0; m < 4; ++m) {
        #pragma unroll
        for (int r4 = 0; r4 < 4; ++r4) {
            const int idx = m * 4 + r4;
            const int i = i0 + wm + m * 16 + (lane >> 4) * 4 + r4;
            #pragma unroll
            for (int n = 0; n < 4; ++n) {
                const int j = j0 + wn + n * 16 + (lane & 15);
                float e = __expf(acc[m][n][r4] - rmt[idx]);
                acc[m][n][r4] = e;
                Ef[(size_t)i * TWON + j] = (half_t)(e * 1024.0f);
                rs[idx] += e;
            }
        }
    }
    #pragma unroll
    for (int off = 1; off < 16; off <<= 1)
        #pragma unroll
        for (int idx = 0; idx < 16; ++idx) rs[idx] += __shfl_xor(rs[idx], off);
    // ---- tile max C
    float tmax = rmt[0];
    #pragma unroll
    for (int idx = 1; idx < 16; ++idx) tmax = fmaxf(tmax, rmt[idx]);
    tmax = fmaxf(tmax, __shfl_xor(tmax, 16));
    tmax = fmaxf(tmax, __shfl_xor(tmax, 32));
    __syncthreads();               // rmt reads done; red reusable
    if (((wave & 1) == 0) && (lane & 15) == 0) {
        #pragma unroll
        for (int m = 0; m < 4; ++m)
            #pragma unroll
            for (int r4 = 0; r4 < 4; ++r4) {
                const int r = wm + m * 16 + (lane >> 4) * 4 + r4;
                red[r] = rmt[m * 4 + r4];             // rmt per row
            }
    }
    if ((lane & 15) == 0) {
        #pragma unroll
        for (int m = 0; m < 4; ++m)
            #pragma unroll
            for (int r4 = 0; r4 < 4; ++r4) {
                const int r = wm + m * 16 + (lane >> 4) * 4 + r4;
                red[128 + (wave & 1) * 128 + r] = rs[m * 4 + r4];  // rs halves
            }
    }
    if (lane == 0) red[384 + wave] = tmax;
    __syncthreads();
    const float C = fmaxf(fmaxf(red[384], red[385]), fmaxf(red[386], red[387]));
    // ---- col partials relative to C: cs = sum_i E * exp(rmt_i - C)
    float w[16];
    #pragma unroll
    for (int idx = 0; idx < 16; ++idx) w[idx] = __expf(rmt[idx] - C);
    float cs[4] = {};
    #pragma unroll
    for (int m = 0; m < 4; ++m)
        #pragma unroll
        for (int r4 = 0; r4 < 4; ++r4)
            #pragma unroll
            for (int n = 0; n < 4; ++n)
                cs[n] = fmaf(acc[m][n][r4], w[m * 4 + r4], cs[n]);
    #pragma unroll
    for (int off = 16; off < 64; off <<= 1)
        #pragma unroll
        for (int n = 0; n < 4; ++n) cs[n] += __shfl_xor(cs[n], off);
    if (lane < 16) {
        #pragma unroll
        for (int n = 0; n < 4; ++n) {
            const int c = wn + n * 16 + lane;
            red[512 + (wave >> 1) * 128 + c] = cs[n];
        }
    }
    __syncthreads();
    if (t < 128) {
        rpm[(size_t)blockIdx.x * NN + i0 + t] = red[t];
        rps[(size_t)blockIdx.x * NN + i0 + t] = red[128 + t] + red[256 + t];
    } else {
        const int c = t - 128;
        cpm[(size_t)blockIdx.y * TWON + j0 + c] = C;
        cps[(size_t)blockIdx.y * TWON + j0 + c] = red[512 + c] + red[640 + c];
    }
}

// ---------------- combine row partials (64 j-tiles, online) -> rm, rrs
__global__ __launch_bounds__(256)
void row_comb_k(const float* __restrict__ rpm, const float* __restrict__ rps,
                float* __restrict__ rm, float* __restrict__ rrs) {
    int i = blockIdx.x * 256 + threadIdx.x;
    float M = -3.0e38f;
    for (int tt = 0; tt < TWON / 128; ++tt) M = fmaxf(M, rpm[(size_t)tt * NN + i]);
    float S = 0.f;
    for (int tt = 0; tt < TWON / 128; ++tt)
        S += rps[(size_t)tt * NN + i] * __expf(rpm[(size_t)tt * NN + i] - M);
    rm[i] = M; rrs[i] = rsqrtf(S);
}

// ---------------- combine col partials (32 i-tiles) -> Pj = -cm/2 + ln(rcs)
__global__ __launch_bounds__(256)
void col_comb_k(const float* __restrict__ cpm, const float* __restrict__ cps,
                float* __restrict__ Pj) {
    int j = blockIdx.x * 256 + threadIdx.x;
    float M = -3.0e38f;
    for (int tt = 0; tt < NN / 128; ++tt) M = fmaxf(M, cpm[(size_t)tt * TWON + j]);
    float S = 0.f;
    for (int tt = 0; tt < NN / 128; ++tt)
        S += cps[(size_t)tt * TWON + j] * __expf(cpm[(size_t)tt * TWON + j] - M);
    Pj[j] = -0.5f * M - 0.5f * logf(S);    // = -cm/2 + ln(rcs)
}

// ---------------- GEMM2: split-K(8), fused-transform reg-staged A, dbuf LDS.
// Per phase: B frags issued FIRST (counted vmcnt), then next-A loads, MFMA,
// transform+ds_write, barrier. 2 blocks/CU via launch_bounds(512,4).
__global__ __launch_bounds__(512, 4)
void gemm2_k(const half_t* __restrict__ Ef, const half_t* __restrict__ b2t,
             const float* __restrict__ rpm, const float* __restrict__ rm,
             const float* __restrict__ Pj, const float* __restrict__ rrs,
             float* __restrict__ part) {
    __shared__ unsigned char lds[16384];   // 2 x (64x64 f16 A tile, swizzled)
    const int t = threadIdx.x;
    const int wave = t >> 6, lane = t & 63;
    const int sw = blockIdx.x;             // 0..511
    const int kslice = sw & 7;             // one kslice per XCD
    const int i0 = (sw >> 3) * 64;
    const int kbase = kslice * (TWON / KSLICE);   // *1024
    const int wn = wave * 64;
    const int sr = t >> 3;          // staging row 0..63
    const int kc = (t & 7) * 8;     // staging k-offset (halves)
    const int awbyte = sr * 128 + ((kc * 2) ^ ((sr & 7) << 4));
    const int NT = (TWON / KSLICE) / 64;   // 16
    const float rmh = 0.5f * rm[i0 + sr] + 6.9314718f;  // + ln(1024)
    f32x4 acc[4][4] = {};
    half8 aE;
    float4 p0, p1;
    float arg;
    auto LOADA = [&](int it) {
        const int k = kbase + it * 64 + kc;
        aE = *reinterpret_cast<const half8*>(Ef + (size_t)(i0 + sr) * TWON + k);
        p0 = *reinterpret_cast<const float4*>(Pj + k);
        p1 = *reinterpret_cast<const float4*>(Pj + k + 4);
        arg = rpm[(size_t)((kbase + it * 64) >> 7) * NN + i0 + sr] - rmh;
    };
    auto STOREA = [&](int buf) {
        half8 g;
        g[0] = (half_t)((float)aE[0] * __expf(arg + p0.x));
        g[1] = (half_t)((float)aE[1] * __expf(arg + p0.y));
        g[2] = (half_t)((float)aE[2] * __expf(arg + p0.z));
        g[3] = (half_t)((float)aE[3] * __expf(arg + p0.w));
        g[4] = (half_t)((float)aE[4] * __expf(arg + p1.x));
        g[5] = (half_t)((float)aE[5] * __expf(arg + p1.y));
        g[6] = (half_t)((float)aE[6] * __expf(arg + p1.z));
        g[7] = (half_t)((float)aE[7] * __expf(arg + p1.w));
        *reinterpret_cast<half8*>(lds + buf * 8192 + awbyte) = g;
    };
    LOADA(0);
    STOREA(0);
    __syncthreads();
    int cur = 0;
    for (int it = 0; it < NT; ++it) {
        // B fragments FIRST (oldest vmcnt entries -> counted wait, not drain)
        half8 bfr0[4], bfr1[4];
        #pragma unroll
        for (int n = 0; n < 4; ++n) {
            const int d = wn + n * 16 + (lane & 15);
            const half_t* bp = b2t + (size_t)d * TWON + kbase + it * 64 + (lane >> 4) * 8;
            bfr0[n] = *reinterpret_cast<const half8*>(bp);
            bfr1[n] = *reinterpret_cast<const half8*>(bp + 32);
        }
        if (it + 1 < NT) LOADA(it + 1);    // next-A issue (consumed after MFMA)
        #pragma unroll
        for (int kk = 0; kk < 2; ++kk) {
            half8 af[4];
            #pragma unroll
            for (int m = 0; m < 4; ++m) {
                const int row = m * 16 + (lane & 15);
                const int off = cur * 8192 + row * 128 +
                                ((kk * 64 + (lane >> 4) * 16) ^ ((row & 7) << 4));
                af[m] = *reinterpret_cast<const half8*>(lds + off);
            }
            #pragma unroll
            for (int m = 0; m < 4; ++m)
                #pragma unroll
                for (int n = 0; n < 4; ++n)
                    acc[m][n] = mfma16h(af[m], (kk == 0) ? bfr0[n] : bfr1[n], acc[m][n]);
        }
        if (it + 1 < NT) STOREA(cur ^ 1);  // transform + stage into other buffer
        __syncthreads();
        cur ^= 1;
    }
    float* pout = part + (size_t)kslice * NN * DD;
    #pragma unroll
    for (int m = 0; m < 4; ++m) {
        float rf[4];
        #pragma unroll
        for (int r4 = 0; r4 < 4; ++r4) rf[r4] = rrs[i0 + m * 16 + (lane >> 4) * 4 + r4];
        #pragma unroll
        for (int n = 0; n < 4; ++n) {
            const int d = wn + n * 16 + (lane & 15);
            #pragma unroll
            for (int r4 = 0; r4 < 4; ++r4) {
                const int i = i0 + m * 16 + (lane >> 4) * 4 + r4;
                pout[(size_t)i * DD + d] = acc[m][n][r4] * rf[r4];
            }
        }
    }
}

// ---------------- reduce partials (8 slices)
__global__ __launch_bounds__(256)
void reduce_k(const float* __restrict__ part, float* __restrict__ out) {
    const size_t e4 = ((size_t)blockIdx.x * 256 + threadIdx.x) * 4;
    float4 a = *reinterpret_cast<const float4*>(part + e4);
    #pragma unroll
    for (int s = 1; s < KSLICE; ++s) {
        float4 b = *reinterpret_cast<const float4*>(part + (size_t)s * NN * DD + e4);
        a.x += b.x; a.y += b.y; a.z += b.z; a.w += b.w;
    }
    *reinterpret_cast<float4*>(out + e4) = a;
}

extern "C" void kernel_launch(void* const* d_in, const int* in_sizes, int n_in,
                              void* d_out, int out_size, void* d_ws, size_t ws_size,
                              hipStream_t stream) {
    const float* x = (const float*)d_in[0];
    const float* y = (const float*)d_in[1];
    float* out = (float*)d_out;

    char* w = (char*)d_ws;
    const size_t OFF_EF   = 0;                          // Ef f16: 64 MiB
    const size_t OFF_BHI  = 67108864;                   // bhi f16: 8 MiB
    const size_t OFF_B2T  = OFF_BHI + 8388608;          // b2t f16: 8 MiB
    const size_t OFF_PART = OFF_B2T + 8388608;          // part: 8 x 8 MiB = 64 MiB
    const size_t OFF_RPM  = OFF_PART + 67108864;        // 1 MiB each
    const size_t OFF_RPS  = OFF_RPM + 1048576;
    const size_t OFF_CPM  = OFF_RPS + 1048576;
    const size_t OFF_CPS  = OFF_CPM + 1048576;
    const size_t OFF_TAIL = OFF_CPS + 1048576;

    half_t* Ef   = (half_t*)(w + OFF_EF);
    half_t* bhi  = (half_t*)(w + OFF_BHI);
    half_t* b2t  = (half_t*)(w + OFF_B2T);
    float*  part = (float*)(w + OFF_PART);
    float*  rpm  = (float*)(w + OFF_RPM);
    float*  rps  = (float*)(w + OFF_RPS);
    float*  cpm  = (float*)(w + OFF_CPM);
    float*  cps  = (float*)(w + OFF_CPS);
    float*  nb   = (float*)(w + OFF_TAIL);              // 8192
    float*  rm   = nb  + TWON;                          // 4096
    float*  rrs  = rm  + NN;                            // 4096
    float*  Pj   = rrs + NN;                            // 8192

    prep_k<<<TWON, 64, 0, stream>>>(x, y, bhi, nb);
    gemm1_k<<<dim3(TWON / 128, NN / 128), 256, 0, stream>>>(bhi, nb, Ef,
                                                            rpm, rps, cpm, cps);
    row_comb_k<<<NN / 256, 256, 0, stream>>>(rpm, rps, rm, rrs);
    col_comb_k<<<TWON / 256, 256, 0, stream>>>(cpm, cps, Pj);
    b2t_k<<<dim3(TWON / 32, DD / 32), dim3(32, 8), 0, stream>>>(x, y, b2t);
    gemm2_k<<<512, 512, 0, stream>>>(Ef, b2t, rpm, rm, Pj, rrs, part);
    reduce_k<<<(NN * DD / 4) / 256, 256, 0, stream>>>(part, out);
}

// Round 12
// 188.781 us; speedup vs baseline: 1.1281x; 1.0376x over previous
//
#include <hip/hip_runtime.h>
#include <math.h>

#define NN   4096
#define DD   512
#define TWON 8192
#define KSLICE 8

typedef _Float16 half_t;
typedef unsigned short u16;
using half8  = __attribute__((ext_vector_type(8))) half_t;
using short8 = __attribute__((ext_vector_type(8))) short;
using f32x4  = __attribute__((ext_vector_type(4))) float;

__device__ __forceinline__ u16 f2bf(float f) {
    unsigned u = __float_as_uint(f);
    u += 0x7fffu + ((u >> 16) & 1u);
    return (u16)(u >> 16);
}
__device__ __forceinline__ float bf2f(u16 h) {
    return __uint_as_float(((unsigned)h) << 16);
}
__device__ __forceinline__ void gl16(const void* g, void* l) {
    __builtin_amdgcn_global_load_lds(
        (const __attribute__((address_space(1))) void*)g,
        (__attribute__((address_space(3))) void*)l, 16, 0, 0);
}
__device__ __forceinline__ f32x4 mfma16h(half8 a, half8 b, f32x4 c) {
    return __builtin_amdgcn_mfma_f32_16x16x32_f16(a, b, c, 0, 0, 0);
}
__device__ __forceinline__ f32x4 mfma16b(short8 a, short8 b, f32x4 c) {
    return __builtin_amdgcn_mfma_f32_16x16x32_bf16(a, b, c, 0, 0, 0);
}

// ---------------- prep: b=[y;x] -> f16 + norms nb[8192]
__global__ __launch_bounds__(64)
void prep_k(const float* __restrict__ x, const float* __restrict__ y,
            half_t* __restrict__ bhi, float* __restrict__ nb) {
    int r = blockIdx.x;           // 0..8191
    int l = threadIdx.x;          // 64
    const float* src = (r < NN) ? (y + (size_t)r * DD) : (x + (size_t)(r - NN) * DD);
    float4 v0 = *reinterpret_cast<const float4*>(src + l * 8);
    float4 v1 = *reinterpret_cast<const float4*>(src + l * 8 + 4);
    float e[8] = {v0.x, v0.y, v0.z, v0.w, v1.x, v1.y, v1.z, v1.w};
    float s = 0.f;
    half8 h;
    #pragma unroll
    for (int q = 0; q < 8; ++q) {
        s += e[q] * e[q];
        h[q] = (half_t)e[q];
    }
    *reinterpret_cast<half8*>(bhi + (size_t)r * DD + l * 8) = h;
    #pragma unroll
    for (int off = 32; off; off >>= 1) s += __shfl_down(s, off);
    if (l == 0) nb[r] = s;
}

// ---------------- b2t: b2t[d][k] = k<N ? y[k][d] : -x[k-N][d]  (bf16, 512x8192)
__global__ __launch_bounds__(256)
void b2t_k(const float* __restrict__ x, const float* __restrict__ y, u16* __restrict__ b2t) {
    __shared__ float tl[32][33];
    int k0 = blockIdx.x * 32, d0 = blockIdx.y * 32;
    int tx = threadIdx.x, ty = threadIdx.y;   // (32,8)
    const float* src = (k0 < NN) ? y : x;
    int row0 = (k0 < NN) ? k0 : (k0 - NN);
    #pragma unroll
    for (int j = 0; j < 4; ++j)
        tl[ty + 8 * j][tx] = src[(size_t)(row0 + ty + 8 * j) * DD + d0 + tx];
    __syncthreads();
    float sgn = (k0 < NN) ? 1.f : -1.f;
    #pragma unroll
    for (int j = 0; j < 4; ++j) {
        float v = tl[tx][ty + 8 * j] * sgn;
        b2t[(size_t)(d0 + ty + 8 * j) * TWON + k0 + tx] = f2bf(v);
    }
}

// ---------------- GEMM1: f16 MFMA + logits; shared-C epilogue (round-8 proven);
// stores E=exp(l-C) as bf16, Ct per tile, rpm=C / rps=row sums, cpm=C / cps=col sums.
__global__ __launch_bounds__(256)
void gemm1_k(const half_t* __restrict__ bhi,
             const float* __restrict__ nb, u16* __restrict__ Ef,
             float* __restrict__ Ct,
             float* __restrict__ rpm, float* __restrict__ rps,
             float* __restrict__ cpm, float* __restrict__ cps) {
    __shared__ unsigned char lds[32768]; // Ahi@0 Bhi@16K, each 128x64 f16 swizzled
    const int t = threadIdx.x;
    const int wave = t >> 6, lane = t & 63;
    const int i0 = blockIdx.y * 128, j0 = blockIdx.x * 128;
    const int wm = (wave >> 1) * 64, wn = (wave & 1) * 64;
    const half_t* ahig = bhi + (size_t)NN * DD;  // x rows are b rows 4096..8191
    f32x4 acc[4][4] = {};
    for (int k0 = 0; k0 < DD; k0 += 64) {
        __syncthreads();
        #pragma unroll
        for (int q = 0; q < 4; ++q) {
            const int dbase = (wave * 4 + q) * 1024;
            const int p  = dbase + lane * 16;
            const int r  = p >> 7;
            const int cb = (p & 127) ^ ((r & 7) << 4);
            const size_t offA = (size_t)(i0 + r) * DD + k0 + (cb >> 1);
            const size_t offB = (size_t)(j0 + r) * DD + k0 + (cb >> 1);
            gl16(ahig + offA, lds + dbase);
            gl16(bhi  + offB, lds + 16384 + dbase);
        }
        asm volatile("s_waitcnt vmcnt(0)" ::: "memory");
        __builtin_amdgcn_sched_barrier(0);
        __syncthreads();
        #pragma unroll
        for (int kk = 0; kk < 2; ++kk) {
            half8 ah[4];
            #pragma unroll
            for (int m = 0; m < 4; ++m) {
                const int row = wm + m * 16 + (lane & 15);
                const int off = row * 128 + ((kk * 64 + (lane >> 4) * 16) ^ ((row & 7) << 4));
                ah[m] = *reinterpret_cast<const half8*>(lds + off);
            }
            #pragma unroll
            for (int n = 0; n < 4; ++n) {
                const int row = wn + n * 16 + (lane & 15);
                const int off = row * 128 + ((kk * 64 + (lane >> 4) * 16) ^ ((row & 7) << 4));
                half8 bh = *reinterpret_cast<const half8*>(lds + 16384 + off);
                #pragma unroll
                for (int m = 0; m < 4; ++m)
                    acc[m][n] = mfma16h(ah[m], bh, acc[m][n]);
            }
        }
    }
    // ---- pass 1: acc -> logits, track thread max
    float nbj[4];
    #pragma unroll
    for (int n = 0; n < 4; ++n) nbj[n] = nb[j0 + wn + n * 16 + (lane & 15)];
    float tmax = -3.0e38f;
    #pragma unroll
    for (int m = 0; m < 4; ++m) {
        #pragma unroll
        for (int r4 = 0; r4 < 4; ++r4) {
            const int i = i0 + wm + m * 16 + (lane >> 4) * 4 + r4;
            const float nxi = nb[NN + i];
            #pragma unroll
            for (int n = 0; n < 4; ++n) {
                const int j = j0 + wn + n * 16 + (lane & 15);
                float sq = nxi + nbj[n] - 2.0f * acc[m][n][r4];
                float lg = -10.0f * sqrtf(fmaxf(sq, 1e-12f));
                if (j == i + NN) lg = -1e7f;
                acc[m][n][r4] = lg;
                tmax = fmaxf(tmax, lg);
            }
        }
    }
    // ---- block-wide shared max C
    #pragma unroll
    for (int off = 1; off < 64; off <<= 1) tmax = fmaxf(tmax, __shfl_xor(tmax, off));
    __syncthreads();
    float* red = reinterpret_cast<float*>(lds);
    if (lane == 0) red[wave] = tmax;
    __syncthreads();
    const float C = fmaxf(fmaxf(red[0], red[1]), fmaxf(red[2], red[3]));
    __syncthreads();
    if (t == 0) Ct[blockIdx.y * 64 + blockIdx.x] = C;
    // ---- pass 2: single exp; store bf16 E; row/col partial sums (pure adds)
    float rs[16] = {}, cs[4] = {};
    #pragma unroll
    for (int m = 0; m < 4; ++m)
        #pragma unroll
        for (int r4 = 0; r4 < 4; ++r4) {
            const int idx = m * 4 + r4;
            const int i = i0 + wm + m * 16 + (lane >> 4) * 4 + r4;
            #pragma unroll
            for (int n = 0; n < 4; ++n) {
                const int j = j0 + wn + n * 16 + (lane & 15);
                float e = __expf(acc[m][n][r4] - C);
                Ef[(size_t)i * TWON + j] = f2bf(e);
                rs[idx] += e;
                cs[n]   += e;
            }
        }
    #pragma unroll
    for (int off = 1; off < 16; off <<= 1) {
        #pragma unroll
        for (int idx = 0; idx < 16; ++idx) rs[idx] += __shfl_xor(rs[idx], off);
    }
    #pragma unroll
    for (int off = 16; off < 64; off <<= 1) {
        #pragma unroll
        for (int n = 0; n < 4; ++n) cs[n] += __shfl_xor(cs[n], off);
    }
    // ---- cross-wave combine: rows red[0..255], cols red[256..511]
    if ((lane & 15) == 0) {
        #pragma unroll
        for (int m = 0; m < 4; ++m)
            #pragma unroll
            for (int r4 = 0; r4 < 4; ++r4) {
                const int r = wm + m * 16 + (lane >> 4) * 4 + r4;
                red[(wave & 1) * 128 + r] = rs[m * 4 + r4];
            }
    }
    if (lane < 16) {
        #pragma unroll
        for (int n = 0; n < 4; ++n) {
            const int c = wn + n * 16 + lane;
            red[256 + (wave >> 1) * 128 + c] = cs[n];
        }
    }
    __syncthreads();
    if (t < 128) {
        float S = red[t] + red[128 + t];
        rpm[(size_t)blockIdx.x * NN + i0 + t] = C;
        rps[(size_t)blockIdx.x * NN + i0 + t] = S;
    } else {
        const int c = t - 128;
        float S = red[256 + c] + red[384 + c];
        cpm[(size_t)blockIdx.y * TWON + j0 + c] = C;
        cps[(size_t)blockIdx.y * TWON + j0 + c] = S;
    }
}

// ---------------- combine row partials (64 j-tiles, online) -> rm, rrs
__global__ __launch_bounds__(256)
void row_comb_k(const float* __restrict__ rpm, const float* __restrict__ rps,
                float* __restrict__ rm, float* __restrict__ rrs) {
    int i = blockIdx.x * 256 + threadIdx.x;
    float M = -3.0e38f;
    for (int tt = 0; tt < TWON / 128; ++tt) M = fmaxf(M, rpm[(size_t)tt * NN + i]);
    float S = 0.f;
    for (int tt = 0; tt < TWON / 128; ++tt)
        S += rps[(size_t)tt * NN + i] * __expf(rpm[(size_t)tt * NN + i] - M);
    rm[i] = M; rrs[i] = rsqrtf(S);
}

// ---------------- combine col partials (32 i-tiles) -> Pj = -cm/2 + ln(rcs)
__global__ __launch_bounds__(256)
void col_comb_k(const float* __restrict__ cpm, const float* __restrict__ cps,
                float* __restrict__ Pj) {
    int j = blockIdx.x * 256 + threadIdx.x;
    float M = -3.0e38f;
    for (int tt = 0; tt < NN / 128; ++tt) M = fmaxf(M, cpm[(size_t)tt * TWON + j]);
    float S = 0.f;
    for (int tt = 0; tt < NN / 128; ++tt)
        S += cps[(size_t)tt * TWON + j] * __expf(cpm[(size_t)tt * TWON + j] - M);
    Pj[j] = -0.5f * M - 0.5f * logf(S);    // = -cm/2 + ln(rcs)
}

// ---------------- GEMM2: split-K(8), fused-transform reg-staged A (bf16),
// dbuf LDS; B frags issued FIRST each phase (counted vmcnt); rrs at epilogue.
__global__ __launch_bounds__(512, 4)
void gemm2_k(const u16* __restrict__ Ef, const u16* __restrict__ b2t,
             const float* __restrict__ Ct, const float* __restrict__ rm,
             const float* __restrict__ Pj, const float* __restrict__ rrs,
             float* __restrict__ part) {
    __shared__ unsigned char lds[16384];   // 2 x (64x64 bf16 A tile, swizzled)
    const int t = threadIdx.x;
    const int wave = t >> 6, lane = t & 63;
    const int sw = blockIdx.x;             // 0..511
    const int kslice = sw & 7;             // one kslice per XCD
    const int i0 = (sw >> 3) * 64;
    const int ib = (sw >> 3) >> 1;         // gemm1 128-row tile index
    const int kbase = kslice * (TWON / KSLICE);   // *1024
    const int wn = wave * 64;
    const int sr = t >> 3;          // staging row 0..63
    const int kc = (t & 7) * 8;     // staging k-offset (elements)
    const int awbyte = sr * 128 + ((kc * 2) ^ ((sr & 7) << 4));
    const int NT = (TWON / KSLICE) / 64;   // 16
    const float rmh = 0.5f * rm[i0 + sr];
    f32x4 acc[4][4] = {};
    short8 aE;
    float4 p0, p1;
    float arg;
    auto LOADA = [&](int it) {
        const int k = kbase + it * 64 + kc;
        aE = *reinterpret_cast<const short8*>(Ef + (size_t)(i0 + sr) * TWON + k);
        p0 = *reinterpret_cast<const float4*>(Pj + k);
        p1 = *reinterpret_cast<const float4*>(Pj + k + 4);
        arg = Ct[ib * 64 + ((kbase + it * 64) >> 7)] - rmh;
    };
    auto STOREA = [&](int buf) {
        short8 g;
        g[0] = (short)f2bf(bf2f((u16)aE[0]) * __expf(arg + p0.x));
        g[1] = (short)f2bf(bf2f((u16)aE[1]) * __expf(arg + p0.y));
        g[2] = (short)f2bf(bf2f((u16)aE[2]) * __expf(arg + p0.z));
        g[3] = (short)f2bf(bf2f((u16)aE[3]) * __expf(arg + p0.w));
        g[4] = (short)f2bf(bf2f((u16)aE[4]) * __expf(arg + p1.x));
        g[5] = (short)f2bf(bf2f((u16)aE[5]) * __expf(arg + p1.y));
        g[6] = (short)f2bf(bf2f((u16)aE[6]) * __expf(arg + p1.z));
        g[7] = (short)f2bf(bf2f((u16)aE[7]) * __expf(arg + p1.w));
        *reinterpret_cast<short8*>(lds + buf * 8192 + awbyte) = g;
    };
    LOADA(0);
    STOREA(0);
    __syncthreads();
    int cur = 0;
    for (int it = 0; it < NT; ++it) {
        // B fragments FIRST (oldest vmcnt entries -> counted wait, not drain)
        short8 bfr0[4], bfr1[4];
        #pragma unroll
        for (int n = 0; n < 4; ++n) {
            const int d = wn + n * 16 + (lane & 15);
            const u16* bp = b2t + (size_t)d * TWON + kbase + it * 64 + (lane >> 4) * 8;
            bfr0[n] = *reinterpret_cast<const short8*>(bp);
            bfr1[n] = *reinterpret_cast<const short8*>(bp + 32);
        }
        if (it + 1 < NT) LOADA(it + 1);    // next-A issue (consumed after MFMA)
        #pragma unroll
        for (int kk = 0; kk < 2; ++kk) {
            short8 af[4];
            #pragma unroll
            for (int m = 0; m < 4; ++m) {
                const int row = m * 16 + (lane & 15);
                const int off = cur * 8192 + row * 128 +
                                ((kk * 64 + (lane >> 4) * 16) ^ ((row & 7) << 4));
                af[m] = *reinterpret_cast<const short8*>(lds + off);
            }
            #pragma unroll
            for (int m = 0; m < 4; ++m)
                #pragma unroll
                for (int n = 0; n < 4; ++n)
                    acc[m][n] = mfma16b(af[m], (kk == 0) ? bfr0[n] : bfr1[n], acc[m][n]);
        }
        if (it + 1 < NT) STOREA(cur ^ 1);  // transform + stage into other buffer
        __syncthreads();
        cur ^= 1;
    }
    float* pout = part + (size_t)kslice * NN * DD;
    #pragma unroll
    for (int m = 0; m < 4; ++m) {
        float rf[4];
        #pragma unroll
        for (int r4 = 0; r4 < 4; ++r4) rf[r4] = rrs[i0 + m * 16 + (lane >> 4) * 4 + r4];
        #pragma unroll
        for (int n = 0; n < 4; ++n) {
            const int d = wn + n * 16 + (lane & 15);
            #pragma unroll
            for (int r4 = 0; r4 < 4; ++r4) {
                const int i = i0 + m * 16 + (lane >> 4) * 4 + r4;
                pout[(size_t)i * DD + d] = acc[m][n][r4] * rf[r4];
            }
        }
    }
}

// ---------------- reduce partials (8 slices)
__global__ __launch_bounds__(256)
void reduce_k(const float* __restrict__ part, float* __restrict__ out) {
    const size_t e4 = ((size_t)blockIdx.x * 256 + threadIdx.x) * 4;
    float4 a = *reinterpret_cast<const float4*>(part + e4);
    #pragma unroll
    for (int s = 1; s < KSLICE; ++s) {
        float4 b = *reinterpret_cast<const float4*>(part + (size_t)s * NN * DD + e4);
        a.x += b.x; a.y += b.y; a.z += b.z; a.w += b.w;
    }
    *reinterpret_cast<float4*>(out + e4) = a;
}

extern "C" void kernel_launch(void* const* d_in, const int* in_sizes, int n_in,
                              void* d_out, int out_size, void* d_ws, size_t ws_size,
                              hipStream_t stream) {
    const float* x = (const float*)d_in[0];
    const float* y = (const float*)d_in[1];
    float* out = (float*)d_out;

    char* w = (char*)d_ws;
    const size_t OFF_EF   = 0;                          // Ef bf16: 64 MiB
    const size_t OFF_BHI  = 67108864;                   // bhi f16: 8 MiB
    const size_t OFF_B2T  = OFF_BHI + 8388608;          // b2t bf16: 8 MiB
    const size_t OFF_PART = OFF_B2T + 8388608;          // part: 8 x 8 MiB
    const size_t OFF_RPM  = OFF_PART + 67108864;        // 1 MiB each
    const size_t OFF_RPS  = OFF_RPM + 1048576;
    const size_t OFF_CPM  = OFF_RPS + 1048576;
    const size_t OFF_CPS  = OFF_CPM + 1048576;
    const size_t OFF_CT   = OFF_CPS + 1048576;          // 8 KiB (+pad)
    const size_t OFF_TAIL = OFF_CT + 65536;

    u16*    Ef   = (u16*)(w + OFF_EF);
    half_t* bhi  = (half_t*)(w + OFF_BHI);
    u16*    b2t  = (u16*)(w + OFF_B2T);
    float*  part = (float*)(w + OFF_PART);
    float*  rpm  = (float*)(w + OFF_RPM);
    float*  rps  = (float*)(w + OFF_RPS);
    float*  cpm  = (float*)(w + OFF_CPM);
    float*  cps  = (float*)(w + OFF_CPS);
    float*  Ct   = (float*)(w + OFF_CT);
    float*  nb   = (float*)(w + OFF_TAIL);              // 8192
    float*  rm   = nb  + TWON;                          // 4096
    float*  rrs  = rm  + NN;                            // 4096
    float*  Pj   = rrs + NN;                            // 8192

    prep_k<<<TWON, 64, 0, stream>>>(x, y, bhi, nb);
    gemm1_k<<<dim3(TWON / 128, NN / 128), 256, 0, stream>>>(bhi, nb, Ef, Ct,
                                                            rpm, rps, cpm, cps);
    row_comb_k<<<NN / 256, 256, 0, stream>>>(rpm, rps, rm, rrs);
    col_comb_k<<<TWON / 256, 256, 0, stream>>>(cpm, cps, Pj);
    b2t_k<<<dim3(TWON / 32, DD / 32), dim3(32, 8), 0, stream>>>(x, y, b2t);
    gemm2_k<<<512, 512, 0, stream>>>(Ef, b2t, Ct, rm, Pj, rrs, part);
    reduce_k<<<(NN * DD / 4) / 256, 256, 0, stream>>>(part, out);
}